// Round 3
// baseline (311.948 us; speedup 1.0000x reference)
//
#include <hip/hip_runtime.h>
#include <hip/hip_bf16.h>

// Sparse Conv3d(32,32,k=2,s=2) kernel-map form:
//   out[out_idx[p], d] += sum_c x[p,c] * W[k_idx[p], c, d]
//
// R5 = R4 with the nontemporal-load type fixed (clang ext_vector, not
// HIP_vector_type). Design: no child-map memset. k=2,s=2 makes
// (out_voxel,k)->point UNIQUE, so conv validates each slot value p via
//   p < n && out_idx[p]==o && k_idx[p]==k
// Stale/poison slot values either fail (treated empty) or accidentally equal
// the unique correct child (still correct). Exact, not probabilistic.
// 2 dispatches: fused prep(W-repack + map write), conv_gather_validate.

typedef __attribute__((ext_vector_type(8))) short bf16x8;   // 8 bf16 = 4 VGPRs
typedef __attribute__((ext_vector_type(4))) float f32x4;    // 4 fp32 (acc + NT loads)

union ABFrag { bf16x8 v; int i[4]; };

__device__ __forceinline__ unsigned short f2bf(float f) {
    union { float f; unsigned u; } v; v.f = f;
    unsigned r = v.u + 0x7FFFu + ((v.u >> 16) & 1u);   // RNE
    return (unsigned short)(r >> 16);
}

// Fused: W[k][c][d] (fp32) -> WB bf16 B-fragment order (threads 0..8191),
// and inverse map child[o][k] = p (plain stores; each (o,k) slot owned by
// exactly one point because kernel=2, stride=2). No init required: conv
// validates slot contents.
__global__ __launch_bounds__(256) void prep_and_map_kernel(
    const float* __restrict__ W, unsigned short* __restrict__ WB,
    const int* __restrict__ k_idx, const int* __restrict__ out_idx,
    int* __restrict__ child, int n)
{
    int t = blockIdx.x * blockDim.x + threadIdx.x;
    if (t < 8 * 2 * 64 * 8) {
        // WB[((k*2+half)*64 + lane)*8 + j] =
        //   bf16(W[k][(lane>>4)*8 + j][half*16 + (lane&15)])
        int j    = t & 7;
        int lane = (t >> 3) & 63;
        int half = (t >> 9) & 1;
        int k    = t >> 10;
        int c = (lane >> 4) * 8 + j;
        int d = half * 16 + (lane & 15);
        WB[t] = f2bf(W[k * 1024 + c * 32 + d]);
    }
    if (t < n) child[(size_t)out_idx[t] * 8 + k_idx[t]] = t;
}

__global__ __launch_bounds__(256) void conv_gather_kernel(
    const float* __restrict__ x,
    const unsigned short* __restrict__ WB,
    const int* __restrict__ child,
    const int* __restrict__ k_idx,
    const int* __restrict__ out_idx,
    float* __restrict__ out,
    int num_out, int n)
{
    const int lane  = threadIdx.x & 63;
    const int wv    = threadIdx.x >> 6;
    const int obase = (blockIdx.x * 4 + wv) * 16;     // 16 out voxels per wave
    if (obase >= num_out) return;

    const int row  = lane & 15;     // A-frag: m = lane&15 (out voxel within tile)
    const int quad = lane >> 4;     // A-frag: k-cols = quad*8 + j
    const int o = obase + row;

    // All 8 (unvalidated) child indices for this row: one 32B region,
    // redundantly loaded by the 4 quads (same-address -> broadcast).
    int4 c0 = make_int4(-1, -1, -1, -1), c1 = make_int4(-1, -1, -1, -1);
    if (o < num_out) {
        const int4* cp = (const int4*)(child + (size_t)o * 8);
        c0 = cp[0]; c1 = cp[1];
    }
    int pk[8] = {c0.x, c0.y, c0.z, c0.w, c1.x, c1.y, c1.z, c1.w};

    // Validate every slot: genuine iff p<n && out_idx[p]==o && k_idx[p]==k.
    // (uniqueness of (o,k)->p makes this exact even against random poison;
    // an accidental pass IS the correct child.) idx arrays are L2-hot after
    // prep; quad-redundant same-address reads broadcast.
#pragma unroll
    for (int k = 0; k < 8; ++k) {
        unsigned p  = (unsigned)pk[k];
        unsigned pc = p < (unsigned)n ? p : 0u;
        int oi = out_idx[pc];
        int ki = k_idx[pc];
        bool ok = (p < (unsigned)n) && (oi == o) && (ki == k);
        pk[k] = ok ? (int)p : -1;
    }

    // Issue all x gathers up front (8 x 32B per lane in flight).
    // Non-temporal: x is read exactly once, keep L2 for child/idx.
    f32x4 xa[8], xb[8];
#pragma unroll
    for (int k = 0; k < 8; ++k) {
        xa[k] = (f32x4){0.f, 0.f, 0.f, 0.f};
        xb[k] = (f32x4){0.f, 0.f, 0.f, 0.f};
        if (pk[k] >= 0) {
            const f32x4* xp = (const f32x4*)(x + (size_t)pk[k] * 32 + quad * 8);
            xa[k] = __builtin_nontemporal_load(xp);
            xb[k] = __builtin_nontemporal_load(xp + 1);
        }
    }

    f32x4 acc0 = {0.f, 0.f, 0.f, 0.f};   // channels 0..15
    f32x4 acc1 = {0.f, 0.f, 0.f, 0.f};   // channels 16..31

#pragma unroll
    for (int k = 0; k < 8; ++k) {
        ABFrag a;
        a.i[0] = (int)f2bf(xa[k][0]) | ((int)f2bf(xa[k][1]) << 16);
        a.i[1] = (int)f2bf(xa[k][2]) | ((int)f2bf(xa[k][3]) << 16);
        a.i[2] = (int)f2bf(xb[k][0]) | ((int)f2bf(xb[k][1]) << 16);
        a.i[3] = (int)f2bf(xb[k][2]) | ((int)f2bf(xb[k][3]) << 16);
        bf16x8 b0 = *(const bf16x8*)(WB + ((size_t)(k * 2 + 0) * 64 + lane) * 8);
        bf16x8 b1 = *(const bf16x8*)(WB + ((size_t)(k * 2 + 1) * 64 + lane) * 8);
        acc0 = __builtin_amdgcn_mfma_f32_16x16x32_bf16(a.v, b0, acc0, 0, 0, 0);
        acc1 = __builtin_amdgcn_mfma_f32_16x16x32_bf16(a.v, b1, acc1, 0, 0, 0);
    }

    // C/D layout: col = lane&15 (channel), row = quad*4 + r (voxel).
    // out written once, never re-read -> non-temporal stores.
#pragma unroll
    for (int r = 0; r < 4; ++r) {
        int oo = obase + quad * 4 + r;
        if (oo < num_out) {
            float* op = out + (size_t)oo * 32 + (lane & 15);
            __builtin_nontemporal_store(acc0[r], op);
            __builtin_nontemporal_store(acc1[r], op + 16);
        }
    }
}

// ---- fallback (atomic scatter) in case ws_size can't hold the map ----
__global__ __launch_bounds__(256) void conv_atomic_kernel(
    const float* __restrict__ x, const unsigned short* __restrict__ WB,
    const int* __restrict__ k_idx, const int* __restrict__ out_idx,
    float* __restrict__ out, int n)
{
    const int lane = threadIdx.x & 63;
    const int wv   = threadIdx.x >> 6;
    const int base = (blockIdx.x * 4 + wv) * 16;
    if (base >= n) return;
    const int row = lane & 15, quad = lane >> 4;
    const int p = base + row;
    int krow = -1;
    ABFrag a; a.i[0] = a.i[1] = a.i[2] = a.i[3] = 0;
    if (p < n) {
        krow = k_idx[p];
        const float* xp = x + (size_t)p * 32 + quad * 8;
        float4 x0 = *(const float4*)xp;
        float4 x1 = *(const float4*)(xp + 4);
        a.i[0] = (int)f2bf(x0.x) | ((int)f2bf(x0.y) << 16);
        a.i[1] = (int)f2bf(x0.z) | ((int)f2bf(x0.w) << 16);
        a.i[2] = (int)f2bf(x1.x) | ((int)f2bf(x1.y) << 16);
        a.i[3] = (int)f2bf(x1.z) | ((int)f2bf(x1.w) << 16);
    }
    f32x4 acc0 = {0.f,0.f,0.f,0.f}, acc1 = {0.f,0.f,0.f,0.f};
#pragma unroll
    for (int k = 0; k < 8; ++k) {
        bf16x8 b0 = *(const bf16x8*)(WB + ((size_t)(k*2+0)*64 + lane)*8);
        bf16x8 b1 = *(const bf16x8*)(WB + ((size_t)(k*2+1)*64 + lane)*8);
        const bool keep = (krow == k);
        ABFrag ak;
        ak.i[0] = keep ? a.i[0] : 0; ak.i[1] = keep ? a.i[1] : 0;
        ak.i[2] = keep ? a.i[2] : 0; ak.i[3] = keep ? a.i[3] : 0;
        acc0 = __builtin_amdgcn_mfma_f32_16x16x32_bf16(ak.v, b0, acc0, 0, 0, 0);
        acc1 = __builtin_amdgcn_mfma_f32_16x16x32_bf16(ak.v, b1, acc1, 0, 0, 0);
    }
#pragma unroll
    for (int r = 0; r < 4; ++r) {
        int p2 = base + quad * 4 + r;
        if (p2 < n) {
            int oi = out_idx[p2];
            float* op = out + (size_t)oi * 32 + (lane & 15);
            atomicAdd(op,      acc0[r]);
            atomicAdd(op + 16, acc1[r]);
        }
    }
}

extern "C" void kernel_launch(void* const* d_in, const int* in_sizes, int n_in,
                              void* d_out, int out_size, void* d_ws, size_t ws_size,
                              hipStream_t stream) {
    const float* x       = (const float*)d_in[0];
    const float* W       = (const float*)d_in[1];
    const int*   k_idx   = (const int*)d_in[2];
    const int*   out_idx = (const int*)d_in[3];
    const int n = in_sizes[2];
    const int num_out = out_size / 32;           // C=32 channels per voxel
    float* out = (float*)d_out;

    unsigned short* WB = (unsigned short*)d_ws;  // 16 KB repacked W
    const size_t wb_bytes = 16384;
    int* child = (int*)((char*)d_ws + wb_bytes); // num_out*8 ints
    const size_t child_bytes = (size_t)num_out * 8 * sizeof(int);

    if (ws_size >= wb_bytes + child_bytes) {
        // ---- atomic-free path: 2 dispatches, no memset (validated map) ----
        int total = n > 8192 ? n : 8192;
        prep_and_map_kernel<<<(total + 255) / 256, 256, 0, stream>>>(
            W, WB, k_idx, out_idx, child, n);
        int blocks = (num_out + 63) / 64;                        // 64 voxels/block
        conv_gather_kernel<<<blocks, 256, 0, stream>>>(
            x, WB, child, k_idx, out_idx, out, num_out, n);
    } else {
        // ---- fallback: atomic scatter (prep via fused kernel, n=0 -> W only) ----
        prep_and_map_kernel<<<32, 256, 0, stream>>>(W, WB, k_idx, out_idx,
                                                    (int*)nullptr, 0);
        (void)hipMemsetAsync(d_out, 0, (size_t)out_size * sizeof(float), stream);
        int blocks = (n + 63) / 64;
        conv_atomic_kernel<<<blocks, 256, 0, stream>>>(x, WB, k_idx, out_idx, out, n);
    }
}

// Round 4
// 184.056 us; speedup vs baseline: 1.6949x; 1.6949x over previous
//
#include <hip/hip_runtime.h>
#include <hip/hip_bf16.h>

// Sparse Conv3d(32,32,k=2,s=2) kernel-map form:
//   out[out_idx[p], d] += sum_c x[p,c] * W[k_idx[p], c, d]
//
// R6: revert R5's regressions (validated map -> memset'd map; NT x loads ->
// cached loads), and restructure the conv gather around
// __builtin_amdgcn_global_load_lds: per-lane global gather addresses, linear
// LDS destination, ZERO data VGPRs. Outstanding loads are vmcnt-tracked, not
// register-bound -> ~10 waves/CU and ~60KB in flight/CU instead of 2
// waves/SIMD and 4KB. Dispatches: memset(child), fused prep, conv.

typedef __attribute__((ext_vector_type(8))) short bf16x8;   // 8 bf16 = 4 VGPRs
typedef __attribute__((ext_vector_type(4))) float f32x4;    // 4 fp32

union ABFrag { bf16x8 v; int i[4]; };

__device__ __forceinline__ unsigned short f2bf(float f) {
    union { float f; unsigned u; } v; v.f = f;
    unsigned r = v.u + 0x7FFFu + ((v.u >> 16) & 1u);   // RNE
    return (unsigned short)(r >> 16);
}

// Per-lane global gather -> linear LDS (dest = wave-uniform base + lane*16).
__device__ __forceinline__ void gld16(const void* g, void* l) {
    __builtin_amdgcn_global_load_lds(
        (const __attribute__((address_space(1))) unsigned int*)g,
        (__attribute__((address_space(3))) unsigned int*)l, 16, 0, 0);
}

// Fused: W[k][c][d] (fp32) -> WB bf16 B-fragment order (threads 0..8191),
// and inverse map child[o][k] = p (plain stores; each (o,k) slot owned by
// exactly one point because kernel=2, stride=2).
__global__ __launch_bounds__(256) void prep_and_map_kernel(
    const float* __restrict__ W, unsigned short* __restrict__ WB,
    const int* __restrict__ k_idx, const int* __restrict__ out_idx,
    int* __restrict__ child, int n)
{
    int t = blockIdx.x * blockDim.x + threadIdx.x;
    if (t < 8 * 2 * 64 * 8) {
        // WB[((k*2+half)*64 + lane)*8 + j] =
        //   bf16(W[k][(lane>>4)*8 + j][half*16 + (lane&15)])
        int j    = t & 7;
        int lane = (t >> 3) & 63;
        int half = (t >> 9) & 1;
        int k    = t >> 10;
        int c = (lane >> 4) * 8 + j;
        int d = half * 16 + (lane & 15);
        WB[t] = f2bf(W[k * 1024 + c * 32 + d]);
    }
    if (t < n) child[(size_t)out_idx[t] * 8 + k_idx[t]] = t;
}

// 128 threads = 2 waves/block, 16 out voxels per wave, 32 KB LDS/block
// -> 5 blocks/CU (LDS-limited), ~10 waves/CU.
__global__ __launch_bounds__(128) void conv_gather_kernel(
    const float* __restrict__ x,
    const unsigned short* __restrict__ WB,
    const int* __restrict__ child,
    float* __restrict__ out,
    int num_out)
{
    __shared__ __align__(16) unsigned char smem[2 * 16384];

    const int lane  = threadIdx.x & 63;
    const int wv    = threadIdx.x >> 6;
    const int obase = (blockIdx.x * 2 + wv) * 16;     // 16 out voxels per wave
    if (obase >= num_out) return;

    const int row  = lane & 15;     // A-frag: m = lane&15 (out voxel in tile)
    const int quad = lane >> 4;     // A-frag: k-cols = quad*8 + j
    const int o = obase + row;

    // All 8 child indices for this row: one 32B region, redundantly loaded
    // by the 4 quads (same-address -> broadcast, L1-hot).
    int4 c0 = make_int4(-1, -1, -1, -1), c1 = make_int4(-1, -1, -1, -1);
    if (o < num_out) {
        const int4* cp = (const int4*)(child + (size_t)o * 8);
        c0 = cp[0]; c1 = cp[1];
    }
    int pk[8] = {c0.x, c0.y, c0.z, c0.w, c1.x, c1.y, c1.z, c1.w};

    // Stage all 8 k-tiles into this wave's private 16 KB LDS region.
    // Issue I (I=0,1) of k: lane L fetches x[pk_row(L&15)] bytes
    // [I*64 + (L>>4)*16, +16) -> LDS k*2048 + I*1024 + L*16.
    // Per row each issue's 4 quads cover one contiguous 64B line (perfect
    // coalescing). Empty slots exec-masked: x traffic stays exactly-once.
    unsigned char* wbuf = smem + wv * 16384;
#pragma unroll
    for (int k = 0; k < 8; ++k) {
        if (pk[k] >= 0) {
            const char* g = (const char*)(x + (size_t)pk[k] * 32) + quad * 16;
            gld16(g,      wbuf + k * 2048);
            gld16(g + 64, wbuf + k * 2048 + 1024);
        }
    }

    // Drain the staging queue; "memory" clobber keeps the ds_reads below.
    asm volatile("s_waitcnt vmcnt(0)" ::: "memory");

    // Frag read-back: lane L's 32B (row L&15, float cols quad*8..+7) sits at
    // k*2048 + quad*512 + row*16 (+256 for the second 16B). 64 distinct 16B
    // slots per read -> minimum structural aliasing.
    const int roff = quad * 512 + row * 16;

    f32x4 acc0 = {0.f, 0.f, 0.f, 0.f};   // channels 0..15
    f32x4 acc1 = {0.f, 0.f, 0.f, 0.f};   // channels 16..31

#pragma unroll
    for (int k = 0; k < 8; ++k) {
        const unsigned char* p0 = wbuf + k * 2048 + roff;
        f32x4 h0 = *(const f32x4*)p0;
        f32x4 h1 = *(const f32x4*)(p0 + 256);
        const int m = (pk[k] >= 0) ? -1 : 0;   // zero empty slots (LDS garbage)
        ABFrag a;
        a.i[0] = (((int)f2bf(h0[0])) | ((int)f2bf(h0[1]) << 16)) & m;
        a.i[1] = (((int)f2bf(h0[2])) | ((int)f2bf(h0[3]) << 16)) & m;
        a.i[2] = (((int)f2bf(h1[0])) | ((int)f2bf(h1[1]) << 16)) & m;
        a.i[3] = (((int)f2bf(h1[2])) | ((int)f2bf(h1[3]) << 16)) & m;
        bf16x8 b0 = *(const bf16x8*)(WB + ((size_t)(k * 2 + 0) * 64 + lane) * 8);
        bf16x8 b1 = *(const bf16x8*)(WB + ((size_t)(k * 2 + 1) * 64 + lane) * 8);
        acc0 = __builtin_amdgcn_mfma_f32_16x16x32_bf16(a.v, b0, acc0, 0, 0, 0);
        acc1 = __builtin_amdgcn_mfma_f32_16x16x32_bf16(a.v, b1, acc1, 0, 0, 0);
    }

    // C/D layout: col = lane&15 (channel), row = quad*4 + r (voxel).
    // out written once, never re-read -> non-temporal stores (keep L2/L3
    // for the x gather stream).
#pragma unroll
    for (int r = 0; r < 4; ++r) {
        int oo = obase + quad * 4 + r;
        if (oo < num_out) {
            float* op = out + (size_t)oo * 32 + (lane & 15);
            __builtin_nontemporal_store(acc0[r], op);
            __builtin_nontemporal_store(acc1[r], op + 16);
        }
    }
}

// ---- fallback (atomic scatter) in case ws_size can't hold the map ----
__global__ __launch_bounds__(256) void conv_atomic_kernel(
    const float* __restrict__ x, const unsigned short* __restrict__ WB,
    const int* __restrict__ k_idx, const int* __restrict__ out_idx,
    float* __restrict__ out, int n)
{
    const int lane = threadIdx.x & 63;
    const int wv   = threadIdx.x >> 6;
    const int base = (blockIdx.x * 4 + wv) * 16;
    if (base >= n) return;
    const int row = lane & 15, quad = lane >> 4;
    const int p = base + row;
    int krow = -1;
    ABFrag a; a.i[0] = a.i[1] = a.i[2] = a.i[3] = 0;
    if (p < n) {
        krow = k_idx[p];
        const float* xp = x + (size_t)p * 32 + quad * 8;
        float4 x0 = *(const float4*)xp;
        float4 x1 = *(const float4*)(xp + 4);
        a.i[0] = (int)f2bf(x0.x) | ((int)f2bf(x0.y) << 16);
        a.i[1] = (int)f2bf(x0.z) | ((int)f2bf(x0.w) << 16);
        a.i[2] = (int)f2bf(x1.x) | ((int)f2bf(x1.y) << 16);
        a.i[3] = (int)f2bf(x1.z) | ((int)f2bf(x1.w) << 16);
    }
    f32x4 acc0 = {0.f,0.f,0.f,0.f}, acc1 = {0.f,0.f,0.f,0.f};
#pragma unroll
    for (int k = 0; k < 8; ++k) {
        bf16x8 b0 = *(const bf16x8*)(WB + ((size_t)(k*2+0)*64 + lane)*8);
        bf16x8 b1 = *(const bf16x8*)(WB + ((size_t)(k*2+1)*64 + lane)*8);
        const bool keep = (krow == k);
        ABFrag ak;
        ak.i[0] = keep ? a.i[0] : 0; ak.i[1] = keep ? a.i[1] : 0;
        ak.i[2] = keep ? a.i[2] : 0; ak.i[3] = keep ? a.i[3] : 0;
        acc0 = __builtin_amdgcn_mfma_f32_16x16x32_bf16(ak.v, b0, acc0, 0, 0, 0);
        acc1 = __builtin_amdgcn_mfma_f32_16x16x32_bf16(ak.v, b1, acc1, 0, 0, 0);
    }
#pragma unroll
    for (int r = 0; r < 4; ++r) {
        int p2 = base + quad * 4 + r;
        if (p2 < n) {
            int oi = out_idx[p2];
            float* op = out + (size_t)oi * 32 + (lane & 15);
            atomicAdd(op,      acc0[r]);
            atomicAdd(op + 16, acc1[r]);
        }
    }
}

extern "C" void kernel_launch(void* const* d_in, const int* in_sizes, int n_in,
                              void* d_out, int out_size, void* d_ws, size_t ws_size,
                              hipStream_t stream) {
    const float* x       = (const float*)d_in[0];
    const float* W       = (const float*)d_in[1];
    const int*   k_idx   = (const int*)d_in[2];
    const int*   out_idx = (const int*)d_in[3];
    const int n = in_sizes[2];
    const int num_out = out_size / 32;           // C=32 channels per voxel
    float* out = (float*)d_out;

    unsigned short* WB = (unsigned short*)d_ws;  // 16 KB repacked W
    const size_t wb_bytes = 16384;
    int* child = (int*)((char*)d_ws + wb_bytes); // num_out*8 ints
    const size_t child_bytes = (size_t)num_out * 8 * sizeof(int);

    if (ws_size >= wb_bytes + child_bytes) {
        // ---- atomic-free path: memset(child) + fused prep + conv ----
        (void)hipMemsetAsync(child, 0xFF, child_bytes, stream);  // child = -1
        int total = n > 8192 ? n : 8192;
        prep_and_map_kernel<<<(total + 255) / 256, 256, 0, stream>>>(
            W, WB, k_idx, out_idx, child, n);
        int blocks = (num_out + 31) / 32;                        // 32 voxels/block
        conv_gather_kernel<<<blocks, 128, 0, stream>>>(x, WB, child, out, num_out);
    } else {
        // ---- fallback: atomic scatter (prep via fused kernel, n=0 -> W only) ----
        prep_and_map_kernel<<<32, 256, 0, stream>>>(W, WB, k_idx, out_idx,
                                                    (int*)nullptr, 0);
        (void)hipMemsetAsync(d_out, 0, (size_t)out_size * sizeof(float), stream);
        int blocks = (n + 63) / 64;
        conv_atomic_kernel<<<blocks, 256, 0, stream>>>(x, WB, k_idx, out_idx, out, n);
    }
}